// Round 12
// baseline (785.974 us; speedup 1.0000x reference)
//
#include <hip/hip_runtime.h>
#include <hip/hip_bf16.h>
#include <cstdint>
#include <cstddef>

typedef __attribute__((ext_vector_type(4)))  float f32x4;
typedef __attribute__((ext_vector_type(8)))  short s16x8;
typedef __attribute__((ext_vector_type(8)))  unsigned short u16x8;
typedef __attribute__((ext_vector_type(4)))  unsigned short u16x4;
typedef unsigned short ushort_t;
typedef unsigned long long u64;

#define MFMA_BF16(a, b, c) __builtin_amdgcn_mfma_f32_16x16x32_bf16((a), (b), (c), 0, 0, 0)

constexpr int BATCH  = 4;
constexpr int SEQ    = 2048;
constexpr int NHEAD  = 16;
constexpr int HEADD  = 64;
constexpr int HID    = 1024;
constexpr int BH     = BATCH * NHEAD;   // 64
constexpr int MROWS  = BATCH * SEQ;     // 8192

// scale folded at Q epilogue: 1/sqrt(64) * log2(e)  (softmax in exp2 domain)
#define QSCALE 0.180336880091961f

// fp32 -> bf16 bits, RNE via compiler
__device__ __forceinline__ ushort_t f2bf(float f) {
  return __builtin_bit_cast(ushort_t, __float2bfloat16(f));
}

// Swizzled Ps offset (ushort elems): row stride 136; chunk XOR keeps both the
// scalar write side and the b128 read side <=2-way bank aliased.
__device__ __forceinline__ int ps_off(int q, int k) {       // Ps[q=0..127][k=0..127]
  return q * 136 + ((((k >> 3) ^ ((q >> 3) & 7)) & 15) << 3) + (k & 7);
}

// global(16B per lane) -> LDS, wave-uniform LDS base + lane*16
__device__ __forceinline__ void gl2lds16(const ushort_t* g, ushort_t* l) {
  __builtin_amdgcn_global_load_lds(
      (const __attribute__((address_space(1))) void*)g,
      (__attribute__((address_space(3))) void*)l, 16, 0, 0);
}

// ---------------------------------------------------------------------------
// Prepack: z=0,1,2 -> convert X[z] (8.4M f32) and W[z] (1M f32) to bf16 (nt);
// z=3 -> mask bit-pack. Pure streaming. Unchanged from R10 (verified good).
// ---------------------------------------------------------------------------
__global__ __launch_bounds__(256) void prepack_kernel(
    const float* __restrict__ q_in, const float* __restrict__ k_in,
    const float* __restrict__ v_in,
    const float* __restrict__ w_q, const float* __restrict__ w_k,
    const float* __restrict__ w_v,
    ushort_t* __restrict__ Xb, ushort_t* __restrict__ Wb,
    const int* __restrict__ mask, u64* __restrict__ pm) {
  const int z = blockIdx.z;
  if (z == 3) {
    const int nwords = BATCH * SEQ * SEQ / 64;  // 262144
    const int lane = threadIdx.x & 63;
    int wid = blockIdx.x * 4 + (threadIdx.x >> 6);
    const int step = gridDim.x * 4;
    for (; wid < nwords; wid += step) {
      int mv = __builtin_nontemporal_load(mask + (size_t)wid * 64 + lane);
      u64 bits = __ballot(mv != 0);
      if (lane == 0) pm[wid] = bits;
    }
    return;
  }
  const float* srcX = (z == 0) ? q_in : (z == 1) ? k_in : v_in;
  const float* srcW = (z == 0) ? w_q : (z == 1) ? w_k : w_v;
  ushort_t* dstX = Xb + (size_t)z * MROWS * HID;
  ushort_t* dstW = Wb + (size_t)z * HID * HID;

  const int tid = blockIdx.x * 256 + threadIdx.x;
  const int stride = gridDim.x * 256;

  for (int u = tid; u < MROWS * HID / 8; u += stride) {
    const float* s = srcX + (size_t)u * 8;
    f32x4 a = __builtin_nontemporal_load((const f32x4*)s);
    f32x4 b = __builtin_nontemporal_load((const f32x4*)(s + 4));
    u16x8 o = {f2bf(a[0]), f2bf(a[1]), f2bf(a[2]), f2bf(a[3]),
               f2bf(b[0]), f2bf(b[1]), f2bf(b[2]), f2bf(b[3])};
    __builtin_nontemporal_store(o, (u16x8*)(dstX + (size_t)u * 8));
  }
  for (int u = tid; u < HID * HID / 8; u += stride) {
    const float* s = srcW + (size_t)u * 8;
    f32x4 a = __builtin_nontemporal_load((const f32x4*)s);
    f32x4 b = __builtin_nontemporal_load((const f32x4*)(s + 4));
    u16x8 o = {f2bf(a[0]), f2bf(a[1]), f2bf(a[2]), f2bf(a[3]),
               f2bf(b[0]), f2bf(b[1]), f2bf(b[2]), f2bf(b[3])};
    __builtin_nontemporal_store(o, (u16x8*)(dstW + (size_t)u * 8));
  }
}

// ---------------------------------------------------------------------------
// Proj GEMM, m97-style. Unchanged from R10 (verified good).
// ---------------------------------------------------------------------------
__global__ __launch_bounds__(256, 4) void proj_gemm_kernel(
    const ushort_t* __restrict__ Xb, const ushort_t* __restrict__ Wb,
    const float* __restrict__ b_q, const float* __restrict__ b_k,
    const float* __restrict__ b_v,
    ushort_t* __restrict__ Qp, ushort_t* __restrict__ Kp,
    ushort_t* __restrict__ Vp) {
  __shared__ ushort_t As[128 * 64];
  __shared__ ushort_t Bs[128 * 64];

  const int z = blockIdx.z;
  const float* bias = (z == 0) ? b_q : (z == 1) ? b_k : b_v;
  const float scale = (z == 0) ? QSCALE : 1.0f;

  const int tid  = threadIdx.x;
  const int lane = tid & 63;
  const int wave = tid >> 6;
  const int wr = wave >> 1, wc = wave & 1;
  const int lo = lane & 15, hi = lane >> 4;
  const int mb = blockIdx.y, nb = blockIdx.x;

  const ushort_t* Ag = Xb + (size_t)z * MROWS * HID + (size_t)mb * 128 * HID;
  const ushort_t* Bg = Wb + (size_t)z * HID * HID + (size_t)nb * 128 * HID;
  const int lrow = lane >> 3, lcol = (lane & 7) * 8;

  f32x4 acc[4][4];
#pragma unroll
  for (int i = 0; i < 4; i++)
#pragma unroll
    for (int j = 0; j < 4; j++) acc[i][j] = (f32x4){0.f, 0.f, 0.f, 0.f};

  for (int k0 = 0; k0 < HID; k0 += 64) {
#pragma unroll
    for (int it = 0; it < 4; it++) {
      const int r0 = (it * 4 + wave) * 8;
      gl2lds16(Ag + (size_t)(r0 + lrow) * HID + k0 + lcol, &As[(it * 4 + wave) * 512]);
      gl2lds16(Bg + (size_t)(r0 + lrow) * HID + k0 + lcol, &Bs[(it * 4 + wave) * 512]);
    }
    __syncthreads();
#pragma unroll
    for (int kk = 0; kk < 2; kk++) {
      const int ko = kk * 32 + hi * 8;
      s16x8 af[4], bf[4];
#pragma unroll
      for (int i = 0; i < 4; i++)
        af[i] = *(const s16x8*)(&As[(wr * 64 + i * 16 + lo) * 64 + ko]);
#pragma unroll
      for (int j = 0; j < 4; j++)
        bf[j] = *(const s16x8*)(&Bs[(wc * 64 + j * 16 + lo) * 64 + ko]);
#pragma unroll
      for (int i = 0; i < 4; i++)
#pragma unroll
        for (int j = 0; j < 4; j++)
          acc[i][j] = MFMA_BF16(af[i], bf[j], acc[i][j]);
    }
    __syncthreads();
  }

  if (z != 2) {
    ushort_t* out = (z == 0) ? Qp : Kp;
#pragma unroll
    for (int j = 0; j < 4; j++) {
      const int n = nb * 128 + wc * 64 + j * 16 + lo;
      const float bvn = bias[n];
      const int h = n >> 6, d = n & 63;
#pragma unroll
      for (int i = 0; i < 4; i++) {
        const int m0 = mb * 128 + wr * 64 + i * 16 + hi * 4;
#pragma unroll
        for (int r = 0; r < 4; r++) {
          const int m = m0 + r;
          const int b = m >> 11, s = m & 2047;
          float v = (acc[i][j][r] + bvn) * scale;
          __builtin_nontemporal_store(
              f2bf(v), out + (((size_t)(b * NHEAD + h) * SEQ) + s) * HEADD + d);
        }
      }
    }
  } else {
#pragma unroll
    for (int j = 0; j < 4; j++) {
      const int n = nb * 128 + wc * 64 + j * 16 + lo;
      const float bvn = bias[n];
      const int h = n >> 6, d = n & 63;
#pragma unroll
      for (int i = 0; i < 4; i++) {
        const int m0 = mb * 128 + wr * 64 + i * 16 + hi * 4;
        const int b = m0 >> 11, s0 = m0 & 2047;
        u16x4 pk = {f2bf(acc[i][j][0] + bvn), f2bf(acc[i][j][1] + bvn),
                    f2bf(acc[i][j][2] + bvn), f2bf(acc[i][j][3] + bvn)};
        __builtin_nontemporal_store(
            pk, (u16x4*)(Vp + ((size_t)(b * NHEAD + h) * HEADD + d) * SEQ + s0));
      }
    }
  }
}

// ---------------------------------------------------------------------------
// attn_pv: EXACT R10 sweep1 + finalize. Exports mi = log2(l) to mi_ws.
// (256,3): 3 blocks/CU by LDS (156.7KB); regalloc capped at 168 VGPR.
// ---------------------------------------------------------------------------
__global__ __launch_bounds__(256, 3) void attn_pv_kernel(
    const ushort_t* __restrict__ Qp, const ushort_t* __restrict__ Kp,
    const ushort_t* __restrict__ Vtg, const u64* __restrict__ pm,
    float* __restrict__ mi_ws, float* __restrict__ ctx) {
  extern __shared__ ushort_t smem[];
  ushort_t* Vt = smem;           // [64][136] linear+pad  = 8704 elems
  ushort_t* Ps = smem + 8704;    // [128][136] swizzled   = 17408 elems

  const int tid  = threadIdx.x;
  const int lane = tid & 63, wave = tid >> 6;
  const int lo = lane & 15, hi = lane >> 4;

  const int f   = blockIdx.x;                 // 0..1023
  const int xcd = f & 7, i5 = f >> 3;         // i5: 0..127
  const int bh  = xcd * 8 + (i5 & 7);
  const int qb  = i5 >> 3;                    // 0..15
  const int b = bh >> 4, h = bh & 15;

  const ushort_t* Qg = Qp + ((size_t)bh * SEQ + qb * 128 + wave * 32) * HEADD;
  s16x8 aq[2][2];
#pragma unroll
  for (int i = 0; i < 2; i++)
#pragma unroll
    for (int kk = 0; kk < 2; kk++)
      aq[i][kk] = *(const s16x8*)(Qg + (size_t)(i * 16 + lo) * HEADD + kk * 32 + hi * 8);

  const ushort_t* Kg = Kp + (size_t)bh * SEQ * HEADD;          // [s][d]
  const ushort_t* Vg = Vtg + (size_t)bh * HEADD * SEQ;         // [d][s]
  const u64* pmb = pm + (size_t)b * SEQ * 32;
  const int q0 = qb * 128 + wave * 32;

  float lrun[2][4];
#pragma unroll
  for (int i = 0; i < 2; i++)
#pragma unroll
    for (int r = 0; r < 4; r++) lrun[i][r] = 0.f;
  f32x4 pacc[2][4];
#pragma unroll
  for (int i = 0; i < 2; i++)
#pragma unroll
    for (int jd = 0; jd < 4; jd++) pacc[i][jd] = (f32x4){0.f, 0.f, 0.f, 0.f};

  const int vr16 = tid >> 4;         // 0..15 (V d-row base)
  const int vc8  = (tid & 15) * 8;   // 0..120 (V s-col)

  for (int kt = 0; kt < SEQ / 128; kt++) {
    u16x8 vreg[4];
#pragma unroll
    for (int it = 0; it < 4; it++)
      vreg[it] = *(const u16x8*)(Vg + (size_t)(it * 16 + vr16) * SEQ + kt * 128 + vc8);

    f32x4 sacc[2][8];
#pragma unroll
    for (int i = 0; i < 2; i++)
#pragma unroll
      for (int j = 0; j < 8; j++) sacc[i][j] = (f32x4){0.f, 0.f, 0.f, 0.f};
#pragma unroll
    for (int j = 0; j < 8; j++) {
      const ushort_t* kr = Kg + (size_t)(kt * 128 + j * 16 + lo) * HEADD + hi * 8;
      s16x8 b0 = *(const s16x8*)(kr);
      s16x8 b1 = *(const s16x8*)(kr + 32);
      sacc[0][j] = MFMA_BF16(aq[0][0], b0, sacc[0][j]);
      sacc[1][j] = MFMA_BF16(aq[1][0], b0, sacc[1][j]);
      sacc[0][j] = MFMA_BF16(aq[0][1], b1, sacc[0][j]);
      sacc[1][j] = MFMA_BF16(aq[1][1], b1, sacc[1][j]);
    }

#pragma unroll
    for (int it = 0; it < 4; it++)
      *(u16x8*)(&Vt[(it * 16 + vr16) * 136 + vc8]) = vreg[it];

#pragma unroll
    for (int i = 0; i < 2; i++)
#pragma unroll
      for (int r = 0; r < 4; r++) {
        const int q = q0 + i * 16 + hi * 4 + r;
        const u64* pw = pmb + (size_t)q * 32 + kt * 2;
        u64 s0 = pw[0] >> lo, s1 = pw[1] >> lo;
        const int prow = wave * 32 + i * 16 + hi * 4 + r;
        float tsum = 0.f;
#pragma unroll
        for (int j = 0; j < 8; j++) {
          unsigned bit = (unsigned)((j < 4 ? (s0 >> (j * 16)) : (s1 >> ((j - 4) * 16))) & 1ull);
          float s = bit ? sacc[i][j][r] : -1e30f;
          float ev = __builtin_amdgcn_exp2f(s);
          tsum += ev;
          Ps[ps_off(prow, j * 16 + lo)] = f2bf(ev);
        }
        lrun[i][r] += tsum;
      }
    __syncthreads();   // Ps + Vt visible

#pragma unroll
    for (int kkp = 0; kkp < 4; kkp++) {
      const int ko = kkp * 32 + hi * 8;
      s16x8 ap0 = *(const s16x8*)(&Ps[ps_off(wave * 32 + lo, ko)]);
      s16x8 ap1 = *(const s16x8*)(&Ps[ps_off(wave * 32 + 16 + lo, ko)]);
#pragma unroll
      for (int jd = 0; jd < 4; jd++) {
        s16x8 bv = *(const s16x8*)(&Vt[(jd * 16 + lo) * 136 + ko]);
        pacc[0][jd] = MFMA_BF16(ap0, bv, pacc[0][jd]);
        pacc[1][jd] = MFMA_BF16(ap1, bv, pacc[1][jd]);
      }
    }
    __syncthreads();   // Ps/Vt consumed before next tile's staging
  }

  // ---- finalize: l, ctx = pacc/l (nt), mi -> ws ----
  float il[2][4];
#pragma unroll
  for (int i = 0; i < 2; i++)
#pragma unroll
    for (int r = 0; r < 4; r++) {
      float l = lrun[i][r];
#pragma unroll
      for (int off = 1; off < 16; off <<= 1) l += __shfl_xor(l, off);
      il[i][r] = 1.0f / l;
      if (lo == 0)
        mi_ws[bh * SEQ + q0 + i * 16 + hi * 4 + r] = __builtin_amdgcn_logf(l);  // log2
    }
#pragma unroll
  for (int i = 0; i < 2; i++)
#pragma unroll
    for (int jd = 0; jd < 4; jd++)
#pragma unroll
      for (int r = 0; r < 4; r++) {
        const int q = q0 + i * 16 + hi * 4 + r;
        __builtin_nontemporal_store(
            pacc[i][jd][r] * il[i][r],
            ctx + ((size_t)b * SEQ + q) * HID + h * HEADD + jd * 16 + lo);
      }
}

// ---------------------------------------------------------------------------
// attn_store: EXACT R10 sweep2 (16x16 path), mi from ws. Zero LDS, zero
// barriers, (256,4) -> ~2x the merged kernel's TLP on the 1.07GB stream.
// ---------------------------------------------------------------------------
__global__ __launch_bounds__(256, 4) void attn_store_kernel(
    const ushort_t* __restrict__ Qp, const ushort_t* __restrict__ Kp,
    const u64* __restrict__ pm, const float* __restrict__ mi_ws,
    float* __restrict__ attn) {
  const int tid  = threadIdx.x;
  const int lane = tid & 63, wave = tid >> 6;
  const int lo = lane & 15, hi = lane >> 4;

  const int f   = blockIdx.x;                 // 0..1023
  const int xcd = f & 7, i5 = f >> 3;         // i5: 0..127
  const int bh  = xcd * 8 + (i5 & 7);
  const int qb  = i5 >> 3;                    // 0..15
  const int b = bh >> 4;

  const ushort_t* Qg = Qp + ((size_t)bh * SEQ + qb * 128 + wave * 32) * HEADD;
  s16x8 aq[2][2];
#pragma unroll
  for (int i = 0; i < 2; i++)
#pragma unroll
    for (int kk = 0; kk < 2; kk++)
      aq[i][kk] = *(const s16x8*)(Qg + (size_t)(i * 16 + lo) * HEADD + kk * 32 + hi * 8);

  const ushort_t* Kg = Kp + (size_t)bh * SEQ * HEADD;          // [s][d]
  const u64* pmb = pm + (size_t)b * SEQ * 32;
  const int q0 = qb * 128 + wave * 32;

  float mi[2][4];
#pragma unroll
  for (int i = 0; i < 2; i++)
#pragma unroll
    for (int r = 0; r < 4; r++)
      mi[i][r] = mi_ws[bh * SEQ + q0 + i * 16 + hi * 4 + r];

  for (int kt = 0; kt < SEQ / 128; kt++) {
    f32x4 sacc[2][8];
#pragma unroll
    for (int i = 0; i < 2; i++)
#pragma unroll
      for (int j = 0; j < 8; j++) sacc[i][j] = (f32x4){0.f, 0.f, 0.f, 0.f};
#pragma unroll
    for (int j = 0; j < 8; j++) {
      const ushort_t* kr = Kg + (size_t)(kt * 128 + j * 16 + lo) * HEADD + hi * 8;
      s16x8 b0 = *(const s16x8*)(kr);
      s16x8 b1 = *(const s16x8*)(kr + 32);
      sacc[0][j] = MFMA_BF16(aq[0][0], b0, sacc[0][j]);
      sacc[1][j] = MFMA_BF16(aq[1][0], b0, sacc[1][j]);
      sacc[0][j] = MFMA_BF16(aq[0][1], b1, sacc[0][j]);
      sacc[1][j] = MFMA_BF16(aq[1][1], b1, sacc[1][j]);
    }
#pragma unroll
    for (int i = 0; i < 2; i++)
#pragma unroll
      for (int r = 0; r < 4; r++) {
        const int q = q0 + i * 16 + hi * 4 + r;
        const u64* pw = pmb + (size_t)q * 32 + kt * 2;
        u64 s0 = pw[0] >> lo, s1 = pw[1] >> lo;
        const size_t abase = ((size_t)bh * SEQ + q) * SEQ + (size_t)kt * 128;
        const float miv = mi[i][r];
#pragma unroll
        for (int j = 0; j < 8; j++) {
          unsigned bit = (unsigned)((j < 4 ? (s0 >> (j * 16)) : (s1 >> ((j - 4) * 16))) & 1ull);
          float s = bit ? sacc[i][j][r] : -1e30f;
          __builtin_nontemporal_store(__builtin_amdgcn_exp2f(s - miv),
                                      attn + abase + j * 16 + lo);
        }
      }
  }
}

// ---------------------------------------------------------------------------
extern "C" void kernel_launch(void* const* d_in, const int* in_sizes, int n_in,
                              void* d_out, int out_size, void* d_ws, size_t ws_size,
                              hipStream_t stream) {
  const float* query  = (const float*)d_in[0];
  const float* key_in = (const float*)d_in[1];
  const float* value  = (const float*)d_in[2];
  const int*   mask   = (const int*)d_in[3];
  const float* w_q = (const float*)d_in[4];
  const float* b_q = (const float*)d_in[5];
  const float* w_k = (const float*)d_in[6];
  const float* b_k = (const float*)d_in[7];
  const float* w_v = (const float*)d_in[8];
  const float* b_v = (const float*)d_in[9];

  char* ws = (char*)d_ws;
  const size_t proj_elems = (size_t)BATCH * NHEAD * SEQ * HEADD;  // 8388608
  ushort_t* Qp = (ushort_t*)ws;
  ushort_t* Kp = Qp + proj_elems;
  ushort_t* Vp = Kp + proj_elems;          // [B][H][D][S] transposed
  u64* pmask   = (u64*)(ws + 3 * proj_elems * sizeof(ushort_t));
  float* mi_ws = (float*)(pmask + (size_t)BATCH * SEQ * SEQ / 64);

  float* ctx  = (float*)d_out;                         // [B][S][HID]
  float* attn = ctx + (size_t)BATCH * SEQ * HID;       // [B][H][S][S]

  // bf16 prepack scratch lives in d_out's attn region (read by the GEMM,
  // overwritten afterwards by attn_store). Sequential + deterministic.
  ushort_t* Xb = (ushort_t*)attn;                         // 3 x 8.4M bf16
  ushort_t* Wb = Xb + (size_t)3 * MROWS * HID;            // 3 x 1M bf16

  prepack_kernel<<<dim3(512, 1, 4), dim3(256), 0, stream>>>(
      query, key_in, value, w_q, w_k, w_v, Xb, Wb, mask, pmask);

  proj_gemm_kernel<<<dim3(HID / 128, MROWS / 128, 3), dim3(256), 0, stream>>>(
      Xb, Wb, b_q, b_k, b_v, Qp, Kp, Vp);

  const size_t lds_pv = (8704 + 17408) * sizeof(ushort_t);  // 52224 B
  attn_pv_kernel<<<dim3(BH * (SEQ / 128)), dim3(256), lds_pv, stream>>>(
      Qp, Kp, Vp, pmask, mi_ws, ctx);

  attn_store_kernel<<<dim3(BH * (SEQ / 128)), dim3(256), 0, stream>>>(
      Qp, Kp, pmask, mi_ws, attn);
}

// Round 13
// 683.912 us; speedup vs baseline: 1.1492x; 1.1492x over previous
//
#include <hip/hip_runtime.h>
#include <hip/hip_bf16.h>
#include <cstdint>
#include <cstddef>

typedef __attribute__((ext_vector_type(4)))  float f32x4;
typedef __attribute__((ext_vector_type(8)))  short s16x8;
typedef __attribute__((ext_vector_type(8)))  unsigned short u16x8;
typedef __attribute__((ext_vector_type(4)))  unsigned short u16x4;
typedef unsigned short ushort_t;
typedef unsigned long long u64;

#define MFMA_BF16(a, b, c) __builtin_amdgcn_mfma_f32_16x16x32_bf16((a), (b), (c), 0, 0, 0)

constexpr int BATCH  = 4;
constexpr int SEQ    = 2048;
constexpr int NHEAD  = 16;
constexpr int HEADD  = 64;
constexpr int HID    = 1024;
constexpr int BH     = BATCH * NHEAD;   // 64
constexpr int MROWS  = BATCH * SEQ;     // 8192

// scale folded at Q epilogue: 1/sqrt(64) * log2(e)  (softmax in exp2 domain)
#define QSCALE 0.180336880091961f

// fp32 -> bf16 bits, RNE via compiler
__device__ __forceinline__ ushort_t f2bf(float f) {
  return __builtin_bit_cast(ushort_t, __float2bfloat16(f));
}

// Swizzled Ps offset (ushort elems): row stride 136; chunk XOR keeps both the
// scalar write side and the b128 read side <=2-way bank aliased.
__device__ __forceinline__ int ps_off(int q, int k) {       // Ps[q=0..127][k=0..127]
  return q * 136 + ((((k >> 3) ^ ((q >> 3) & 7)) & 15) << 3) + (k & 7);
}

// global(16B per lane) -> LDS, wave-uniform LDS base + lane*16
__device__ __forceinline__ void gl2lds16(const ushort_t* g, ushort_t* l) {
  __builtin_amdgcn_global_load_lds(
      (const __attribute__((address_space(1))) void*)g,
      (__attribute__((address_space(3))) void*)l, 16, 0, 0);
}

// ---------------------------------------------------------------------------
// Prepack: z=0,1,2 -> convert X[z] (8.4M f32) and W[z] (1M f32) to bf16 (nt);
// z=3 -> mask bit-pack. Pure streaming. Unchanged from R10 (verified good).
// ---------------------------------------------------------------------------
__global__ __launch_bounds__(256) void prepack_kernel(
    const float* __restrict__ q_in, const float* __restrict__ k_in,
    const float* __restrict__ v_in,
    const float* __restrict__ w_q, const float* __restrict__ w_k,
    const float* __restrict__ w_v,
    ushort_t* __restrict__ Xb, ushort_t* __restrict__ Wb,
    const int* __restrict__ mask, u64* __restrict__ pm) {
  const int z = blockIdx.z;
  if (z == 3) {
    const int nwords = BATCH * SEQ * SEQ / 64;  // 262144
    const int lane = threadIdx.x & 63;
    int wid = blockIdx.x * 4 + (threadIdx.x >> 6);
    const int step = gridDim.x * 4;
    for (; wid < nwords; wid += step) {
      int mv = __builtin_nontemporal_load(mask + (size_t)wid * 64 + lane);
      u64 bits = __ballot(mv != 0);
      if (lane == 0) pm[wid] = bits;
    }
    return;
  }
  const float* srcX = (z == 0) ? q_in : (z == 1) ? k_in : v_in;
  const float* srcW = (z == 0) ? w_q : (z == 1) ? w_k : w_v;
  ushort_t* dstX = Xb + (size_t)z * MROWS * HID;
  ushort_t* dstW = Wb + (size_t)z * HID * HID;

  const int tid = blockIdx.x * 256 + threadIdx.x;
  const int stride = gridDim.x * 256;

  for (int u = tid; u < MROWS * HID / 8; u += stride) {
    const float* s = srcX + (size_t)u * 8;
    f32x4 a = __builtin_nontemporal_load((const f32x4*)s);
    f32x4 b = __builtin_nontemporal_load((const f32x4*)(s + 4));
    u16x8 o = {f2bf(a[0]), f2bf(a[1]), f2bf(a[2]), f2bf(a[3]),
               f2bf(b[0]), f2bf(b[1]), f2bf(b[2]), f2bf(b[3])};
    __builtin_nontemporal_store(o, (u16x8*)(dstX + (size_t)u * 8));
  }
  for (int u = tid; u < HID * HID / 8; u += stride) {
    const float* s = srcW + (size_t)u * 8;
    f32x4 a = __builtin_nontemporal_load((const f32x4*)s);
    f32x4 b = __builtin_nontemporal_load((const f32x4*)(s + 4));
    u16x8 o = {f2bf(a[0]), f2bf(a[1]), f2bf(a[2]), f2bf(a[3]),
               f2bf(b[0]), f2bf(b[1]), f2bf(b[2]), f2bf(b[3])};
    __builtin_nontemporal_store(o, (u16x8*)(dstW + (size_t)u * 8));
  }
}

// ---------------------------------------------------------------------------
// Proj GEMM, m97-style + LDS XOR-swizzle (NEW this round).
// Linear [128][64] tiles are a 16-way bank conflict on fragment ds_read_b128
// (128B row stride). Fix per rule #21/m173: keep the global_load_lds dest
// LINEAR, pre-swizzle the per-lane GLOBAL source (unit ^= row&7), and read
// fragments at physical unit (v ^ (row&7)). 16-way -> 8-way (b128 floor).
// ---------------------------------------------------------------------------
__global__ __launch_bounds__(256, 4) void proj_gemm_kernel(
    const ushort_t* __restrict__ Xb, const ushort_t* __restrict__ Wb,
    const float* __restrict__ b_q, const float* __restrict__ b_k,
    const float* __restrict__ b_v,
    ushort_t* __restrict__ Qp, ushort_t* __restrict__ Kp,
    ushort_t* __restrict__ Vp) {
  __shared__ ushort_t As[128 * 64];
  __shared__ ushort_t Bs[128 * 64];

  const int z = blockIdx.z;
  const float* bias = (z == 0) ? b_q : (z == 1) ? b_k : b_v;
  const float scale = (z == 0) ? QSCALE : 1.0f;

  const int tid  = threadIdx.x;
  const int lane = tid & 63;
  const int wave = tid >> 6;
  const int wr = wave >> 1, wc = wave & 1;
  const int lo = lane & 15, hi = lane >> 4;
  const int mb = blockIdx.y, nb = blockIdx.x;

  const ushort_t* Ag = Xb + (size_t)z * MROWS * HID + (size_t)mb * 128 * HID;
  const ushort_t* Bg = Wb + (size_t)z * HID * HID + (size_t)nb * 128 * HID;
  // staging lane decomposition: row-in-chunk = lane>>3, source unit XOR'd
  // with row&7 so LDS physical unit p = v ^ (row&7).
  const int lrow = lane >> 3;
  const int scol = (((lane & 7) ^ lrow) * 8);     // swizzled source col (elems)

  f32x4 acc[4][4];
#pragma unroll
  for (int i = 0; i < 4; i++)
#pragma unroll
    for (int j = 0; j < 4; j++) acc[i][j] = (f32x4){0.f, 0.f, 0.f, 0.f};

  for (int k0 = 0; k0 < HID; k0 += 64) {
#pragma unroll
    for (int it = 0; it < 4; it++) {
      const int r0 = (it * 4 + wave) * 8;
      gl2lds16(Ag + (size_t)(r0 + lrow) * HID + k0 + scol, &As[(it * 4 + wave) * 512]);
      gl2lds16(Bg + (size_t)(r0 + lrow) * HID + k0 + scol, &Bs[(it * 4 + wave) * 512]);
    }
    __syncthreads();
#pragma unroll
    for (int kk = 0; kk < 2; kk++) {
      // logical unit v = kk*4 + hi; physical = v ^ (row&7), row&7 == lo&7
      const int pu = (((kk * 4 + hi) ^ (lo & 7)) * 8);
      s16x8 af[4], bf[4];
#pragma unroll
      for (int i = 0; i < 4; i++)
        af[i] = *(const s16x8*)(&As[(wr * 64 + i * 16 + lo) * 64 + pu]);
#pragma unroll
      for (int j = 0; j < 4; j++)
        bf[j] = *(const s16x8*)(&Bs[(wc * 64 + j * 16 + lo) * 64 + pu]);
#pragma unroll
      for (int i = 0; i < 4; i++)
#pragma unroll
        for (int j = 0; j < 4; j++)
          acc[i][j] = MFMA_BF16(af[i], bf[j], acc[i][j]);
    }
    __syncthreads();
  }

  if (z != 2) {
    ushort_t* out = (z == 0) ? Qp : Kp;
#pragma unroll
    for (int j = 0; j < 4; j++) {
      const int n = nb * 128 + wc * 64 + j * 16 + lo;
      const float bvn = bias[n];
      const int h = n >> 6, d = n & 63;
#pragma unroll
      for (int i = 0; i < 4; i++) {
        const int m0 = mb * 128 + wr * 64 + i * 16 + hi * 4;
#pragma unroll
        for (int r = 0; r < 4; r++) {
          const int m = m0 + r;
          const int b = m >> 11, s = m & 2047;
          float v = (acc[i][j][r] + bvn) * scale;
          __builtin_nontemporal_store(
              f2bf(v), out + (((size_t)(b * NHEAD + h) * SEQ) + s) * HEADD + d);
        }
      }
    }
  } else {
#pragma unroll
    for (int j = 0; j < 4; j++) {
      const int n = nb * 128 + wc * 64 + j * 16 + lo;
      const float bvn = bias[n];
      const int h = n >> 6, d = n & 63;
#pragma unroll
      for (int i = 0; i < 4; i++) {
        const int m0 = mb * 128 + wr * 64 + i * 16 + hi * 4;
        const int b = m0 >> 11, s0 = m0 & 2047;
        u16x4 pk = {f2bf(acc[i][j][0] + bvn), f2bf(acc[i][j][1] + bvn),
                    f2bf(acc[i][j][2] + bvn), f2bf(acc[i][j][3] + bvn)};
        __builtin_nontemporal_store(
            pk, (u16x4*)(Vp + ((size_t)(b * NHEAD + h) * HEADD + d) * SEQ + s0));
      }
    }
  }
}

// ---------------------------------------------------------------------------
// Fused attention — EXACT R10 (verified best; merged two-sweep, nt stores,
// h-fast XCD order). Untouched this round.
// ---------------------------------------------------------------------------
__global__ __launch_bounds__(256, 2) void fused_attn_kernel(
    const ushort_t* __restrict__ Qp, const ushort_t* __restrict__ Kp,
    const ushort_t* __restrict__ Vtg, const u64* __restrict__ pm,
    float* __restrict__ attn, float* __restrict__ ctx) {
  extern __shared__ ushort_t smem[];
  ushort_t* Vt = smem;           // [64][136] linear+pad  = 8704 elems
  ushort_t* Ps = smem + 8704;    // [128][136] swizzled   = 17408 elems

  const int tid  = threadIdx.x;
  const int lane = tid & 63, wave = tid >> 6;
  const int lo = lane & 15, hi = lane >> 4;

  const int f   = blockIdx.x;                 // 0..1023
  const int xcd = f & 7, i5 = f >> 3;         // i5: 0..127
  const int bh  = xcd * 8 + (i5 & 7);
  const int qb  = i5 >> 3;                    // 0..15
  const int b = bh >> 4, h = bh & 15;

  const ushort_t* Qg = Qp + ((size_t)bh * SEQ + qb * 128 + wave * 32) * HEADD;
  s16x8 aq[2][2];
#pragma unroll
  for (int i = 0; i < 2; i++)
#pragma unroll
    for (int kk = 0; kk < 2; kk++)
      aq[i][kk] = *(const s16x8*)(Qg + (size_t)(i * 16 + lo) * HEADD + kk * 32 + hi * 8);

  const ushort_t* Kg = Kp + (size_t)bh * SEQ * HEADD;          // [s][d]
  const ushort_t* Vg = Vtg + (size_t)bh * HEADD * SEQ;         // [d][s]
  const u64* pmb = pm + (size_t)b * SEQ * 32;
  const int q0 = qb * 128 + wave * 32;

  float lrun[2][4];
#pragma unroll
  for (int i = 0; i < 2; i++)
#pragma unroll
    for (int r = 0; r < 4; r++) lrun[i][r] = 0.f;
  f32x4 pacc[2][4];
#pragma unroll
  for (int i = 0; i < 2; i++)
#pragma unroll
    for (int jd = 0; jd < 4; jd++) pacc[i][jd] = (f32x4){0.f, 0.f, 0.f, 0.f};

  const int vr16 = tid >> 4;         // 0..15 (V d-row base)
  const int vc8  = (tid & 15) * 8;   // 0..120 (V s-col)

  // ================= sweep 1: l + PV (unnormalized) =================
  for (int kt = 0; kt < SEQ / 128; kt++) {
    u16x8 vreg[4];
#pragma unroll
    for (int it = 0; it < 4; it++)
      vreg[it] = *(const u16x8*)(Vg + (size_t)(it * 16 + vr16) * SEQ + kt * 128 + vc8);

    f32x4 sacc[2][8];
#pragma unroll
    for (int i = 0; i < 2; i++)
#pragma unroll
      for (int j = 0; j < 8; j++) sacc[i][j] = (f32x4){0.f, 0.f, 0.f, 0.f};
#pragma unroll
    for (int j = 0; j < 8; j++) {
      const ushort_t* kr = Kg + (size_t)(kt * 128 + j * 16 + lo) * HEADD + hi * 8;
      s16x8 b0 = *(const s16x8*)(kr);
      s16x8 b1 = *(const s16x8*)(kr + 32);
      sacc[0][j] = MFMA_BF16(aq[0][0], b0, sacc[0][j]);
      sacc[1][j] = MFMA_BF16(aq[1][0], b0, sacc[1][j]);
      sacc[0][j] = MFMA_BF16(aq[0][1], b1, sacc[0][j]);
      sacc[1][j] = MFMA_BF16(aq[1][1], b1, sacc[1][j]);
    }

#pragma unroll
    for (int it = 0; it < 4; it++)
      *(u16x8*)(&Vt[(it * 16 + vr16) * 136 + vc8]) = vreg[it];

#pragma unroll
    for (int i = 0; i < 2; i++)
#pragma unroll
      for (int r = 0; r < 4; r++) {
        const int q = q0 + i * 16 + hi * 4 + r;
        const u64* pw = pmb + (size_t)q * 32 + kt * 2;
        u64 s0 = pw[0] >> lo, s1 = pw[1] >> lo;
        const int prow = wave * 32 + i * 16 + hi * 4 + r;
        float tsum = 0.f;
#pragma unroll
        for (int j = 0; j < 8; j++) {
          unsigned bit = (unsigned)((j < 4 ? (s0 >> (j * 16)) : (s1 >> ((j - 4) * 16))) & 1ull);
          float s = bit ? sacc[i][j][r] : -1e30f;
          float ev = __builtin_amdgcn_exp2f(s);
          tsum += ev;
          Ps[ps_off(prow, j * 16 + lo)] = f2bf(ev);
        }
        lrun[i][r] += tsum;
      }
    __syncthreads();   // Ps + Vt visible

#pragma unroll
    for (int kkp = 0; kkp < 4; kkp++) {
      const int ko = kkp * 32 + hi * 8;
      s16x8 ap0 = *(const s16x8*)(&Ps[ps_off(wave * 32 + lo, ko)]);
      s16x8 ap1 = *(const s16x8*)(&Ps[ps_off(wave * 32 + 16 + lo, ko)]);
#pragma unroll
      for (int jd = 0; jd < 4; jd++) {
        s16x8 bv = *(const s16x8*)(&Vt[(jd * 16 + lo) * 136 + ko]);
        pacc[0][jd] = MFMA_BF16(ap0, bv, pacc[0][jd]);
        pacc[1][jd] = MFMA_BF16(ap1, bv, pacc[1][jd]);
      }
    }
    __syncthreads();   // Ps/Vt consumed before next tile's staging
  }

  // ---- finalize l (single shuffle-reduce), ctx = pacc / l (nt) ----
  float il[2][4], mi[2][4];
#pragma unroll
  for (int i = 0; i < 2; i++)
#pragma unroll
    for (int r = 0; r < 4; r++) {
      float l = lrun[i][r];
#pragma unroll
      for (int off = 1; off < 16; off <<= 1) l += __shfl_xor(l, off);
      il[i][r] = 1.0f / l;
      mi[i][r] = __builtin_amdgcn_logf(l);   // log2(l)
    }
#pragma unroll
  for (int i = 0; i < 2; i++)
#pragma unroll
    for (int jd = 0; jd < 4; jd++)
#pragma unroll
      for (int r = 0; r < 4; r++) {
        const int q = q0 + i * 16 + hi * 4 + r;
        __builtin_nontemporal_store(
            pacc[i][jd][r] * il[i][r],
            ctx + ((size_t)b * SEQ + q) * HID + h * HEADD + jd * 16 + lo);
      }

  // ================= sweep 2: attn = exp2(s - log2 l), nt stores ==========
  for (int kt = 0; kt < SEQ / 128; kt++) {
    f32x4 sacc[2][8];
#pragma unroll
    for (int i = 0; i < 2; i++)
#pragma unroll
      for (int j = 0; j < 8; j++) sacc[i][j] = (f32x4){0.f, 0.f, 0.f, 0.f};
#pragma unroll
    for (int j = 0; j < 8; j++) {
      const ushort_t* kr = Kg + (size_t)(kt * 128 + j * 16 + lo) * HEADD + hi * 8;
      s16x8 b0 = *(const s16x8*)(kr);
      s16x8 b1 = *(const s16x8*)(kr + 32);
      sacc[0][j] = MFMA_BF16(aq[0][0], b0, sacc[0][j]);
      sacc[1][j] = MFMA_BF16(aq[1][0], b0, sacc[1][j]);
      sacc[0][j] = MFMA_BF16(aq[0][1], b1, sacc[0][j]);
      sacc[1][j] = MFMA_BF16(aq[1][1], b1, sacc[1][j]);
    }
#pragma unroll
    for (int i = 0; i < 2; i++)
#pragma unroll
      for (int r = 0; r < 4; r++) {
        const int q = q0 + i * 16 + hi * 4 + r;
        const u64* pw = pmb + (size_t)q * 32 + kt * 2;
        u64 s0 = pw[0] >> lo, s1 = pw[1] >> lo;
        const size_t abase = ((size_t)bh * SEQ + q) * SEQ + (size_t)kt * 128;
        const float miv = mi[i][r];
#pragma unroll
        for (int j = 0; j < 8; j++) {
          unsigned bit = (unsigned)((j < 4 ? (s0 >> (j * 16)) : (s1 >> ((j - 4) * 16))) & 1ull);
          float s = bit ? sacc[i][j][r] : -1e30f;
          __builtin_nontemporal_store(__builtin_amdgcn_exp2f(s - miv),
                                      attn + abase + j * 16 + lo);
        }
      }
  }
}

// ---------------------------------------------------------------------------
extern "C" void kernel_launch(void* const* d_in, const int* in_sizes, int n_in,
                              void* d_out, int out_size, void* d_ws, size_t ws_size,
                              hipStream_t stream) {
  const float* query  = (const float*)d_in[0];
  const float* key_in = (const float*)d_in[1];
  const float* value  = (const float*)d_in[2];
  const int*   mask   = (const int*)d_in[3];
  const float* w_q = (const float*)d_in[4];
  const float* b_q = (const float*)d_in[5];
  const float* w_k = (const float*)d_in[6];
  const float* b_k = (const float*)d_in[7];
  const float* w_v = (const float*)d_in[8];
  const float* b_v = (const float*)d_in[9];

  char* ws = (char*)d_ws;
  const size_t proj_elems = (size_t)BATCH * NHEAD * SEQ * HEADD;  // 8388608
  ushort_t* Qp = (ushort_t*)ws;
  ushort_t* Kp = Qp + proj_elems;
  ushort_t* Vp = Kp + proj_elems;          // [B][H][D][S] transposed
  u64* pmask   = (u64*)(ws + 3 * proj_elems * sizeof(ushort_t));

  float* ctx  = (float*)d_out;                         // [B][S][HID]
  float* attn = ctx + (size_t)BATCH * SEQ * HID;       // [B][H][S][S]

  // bf16 prepack scratch lives in d_out's attn region (read by the GEMM,
  // overwritten afterwards by the attn kernel). Sequential + deterministic.
  ushort_t* Xb = (ushort_t*)attn;                         // 3 x 8.4M bf16
  ushort_t* Wb = Xb + (size_t)3 * MROWS * HID;            // 3 x 1M bf16

  prepack_kernel<<<dim3(512, 1, 4), dim3(256), 0, stream>>>(
      query, key_in, value, w_q, w_k, w_v, Xb, Wb, mask, pmask);

  proj_gemm_kernel<<<dim3(HID / 128, MROWS / 128, 3), dim3(256), 0, stream>>>(
      Xb, Wb, b_q, b_k, b_v, Qp, Kp, Vp);

  const size_t lds_attn = (8704 + 17408) * sizeof(ushort_t);  // 52224 B
  fused_attn_kernel<<<dim3(BH * (SEQ / 128)), dim3(256), lds_attn, stream>>>(
      Qp, Kp, Vp, pmask, attn, ctx);
}

// Round 14
// 667.988 us; speedup vs baseline: 1.1766x; 1.0238x over previous
//
#include <hip/hip_runtime.h>
#include <hip/hip_bf16.h>
#include <cstdint>
#include <cstddef>

typedef __attribute__((ext_vector_type(4)))  float f32x4;
typedef __attribute__((ext_vector_type(8)))  short s16x8;
typedef __attribute__((ext_vector_type(8)))  unsigned short u16x8;
typedef __attribute__((ext_vector_type(4)))  unsigned short u16x4;
typedef unsigned short ushort_t;
typedef unsigned long long u64;

#define MFMA_BF16(a, b, c) __builtin_amdgcn_mfma_f32_16x16x32_bf16((a), (b), (c), 0, 0, 0)

constexpr int BATCH  = 4;
constexpr int SEQ    = 2048;
constexpr int NHEAD  = 16;
constexpr int HEADD  = 64;
constexpr int HID    = 1024;
constexpr int BH     = BATCH * NHEAD;   // 64
constexpr int MROWS  = BATCH * SEQ;     // 8192

// scale folded at Q epilogue: 1/sqrt(64) * log2(e)  (softmax in exp2 domain)
#define QSCALE 0.180336880091961f

// fp32 -> bf16 bits, RNE via compiler
__device__ __forceinline__ ushort_t f2bf(float f) {
  return __builtin_bit_cast(ushort_t, __float2bfloat16(f));
}

// Swizzled Ps offset (ushort elems): row stride 136; chunk XOR keeps both the
// scalar write side and the b128 read side <=2-way bank aliased.
__device__ __forceinline__ int ps_off(int q, int k) {       // Ps[q=0..127][k=0..127]
  return q * 136 + ((((k >> 3) ^ ((q >> 3) & 7)) & 15) << 3) + (k & 7);
}

// global(16B per lane) -> LDS, wave-uniform LDS base + lane*16
__device__ __forceinline__ void gl2lds16(const ushort_t* g, ushort_t* l) {
  __builtin_amdgcn_global_load_lds(
      (const __attribute__((address_space(1))) void*)g,
      (__attribute__((address_space(3))) void*)l, 16, 0, 0);
}

// ---------------------------------------------------------------------------
// Prepack: z=0,1,2 -> convert X[z] (8.4M f32) and W[z] (1M f32) to bf16 (nt);
// z=3 -> mask bit-pack. Pure streaming. Unchanged (verified good).
// ---------------------------------------------------------------------------
__global__ __launch_bounds__(256) void prepack_kernel(
    const float* __restrict__ q_in, const float* __restrict__ k_in,
    const float* __restrict__ v_in,
    const float* __restrict__ w_q, const float* __restrict__ w_k,
    const float* __restrict__ w_v,
    ushort_t* __restrict__ Xb, ushort_t* __restrict__ Wb,
    const int* __restrict__ mask, u64* __restrict__ pm) {
  const int z = blockIdx.z;
  if (z == 3) {
    const int nwords = BATCH * SEQ * SEQ / 64;  // 262144
    const int lane = threadIdx.x & 63;
    int wid = blockIdx.x * 4 + (threadIdx.x >> 6);
    const int step = gridDim.x * 4;
    for (; wid < nwords; wid += step) {
      int mv = __builtin_nontemporal_load(mask + (size_t)wid * 64 + lane);
      u64 bits = __ballot(mv != 0);
      if (lane == 0) pm[wid] = bits;
    }
    return;
  }
  const float* srcX = (z == 0) ? q_in : (z == 1) ? k_in : v_in;
  const float* srcW = (z == 0) ? w_q : (z == 1) ? w_k : w_v;
  ushort_t* dstX = Xb + (size_t)z * MROWS * HID;
  ushort_t* dstW = Wb + (size_t)z * HID * HID;

  const int tid = blockIdx.x * 256 + threadIdx.x;
  const int stride = gridDim.x * 256;

  for (int u = tid; u < MROWS * HID / 8; u += stride) {
    const float* s = srcX + (size_t)u * 8;
    f32x4 a = __builtin_nontemporal_load((const f32x4*)s);
    f32x4 b = __builtin_nontemporal_load((const f32x4*)(s + 4));
    u16x8 o = {f2bf(a[0]), f2bf(a[1]), f2bf(a[2]), f2bf(a[3]),
               f2bf(b[0]), f2bf(b[1]), f2bf(b[2]), f2bf(b[3])};
    __builtin_nontemporal_store(o, (u16x8*)(dstX + (size_t)u * 8));
  }
  for (int u = tid; u < HID * HID / 8; u += stride) {
    const float* s = srcW + (size_t)u * 8;
    f32x4 a = __builtin_nontemporal_load((const f32x4*)s);
    f32x4 b = __builtin_nontemporal_load((const f32x4*)(s + 4));
    u16x8 o = {f2bf(a[0]), f2bf(a[1]), f2bf(a[2]), f2bf(a[3]),
               f2bf(b[0]), f2bf(b[1]), f2bf(b[2]), f2bf(b[3])};
    __builtin_nontemporal_store(o, (u16x8*)(dstW + (size_t)u * 8));
  }
}

// ---------------------------------------------------------------------------
// Proj GEMM, m97-style + source-side XOR swizzle (neutral but sound; kept).
// ---------------------------------------------------------------------------
__global__ __launch_bounds__(256, 4) void proj_gemm_kernel(
    const ushort_t* __restrict__ Xb, const ushort_t* __restrict__ Wb,
    const float* __restrict__ b_q, const float* __restrict__ b_k,
    const float* __restrict__ b_v,
    ushort_t* __restrict__ Qp, ushort_t* __restrict__ Kp,
    ushort_t* __restrict__ Vp) {
  __shared__ ushort_t As[128 * 64];
  __shared__ ushort_t Bs[128 * 64];

  const int z = blockIdx.z;
  const float* bias = (z == 0) ? b_q : (z == 1) ? b_k : b_v;
  const float scale = (z == 0) ? QSCALE : 1.0f;

  const int tid  = threadIdx.x;
  const int lane = tid & 63;
  const int wave = tid >> 6;
  const int wr = wave >> 1, wc = wave & 1;
  const int lo = lane & 15, hi = lane >> 4;
  const int mb = blockIdx.y, nb = blockIdx.x;

  const ushort_t* Ag = Xb + (size_t)z * MROWS * HID + (size_t)mb * 128 * HID;
  const ushort_t* Bg = Wb + (size_t)z * HID * HID + (size_t)nb * 128 * HID;
  const int lrow = lane >> 3;
  const int scol = (((lane & 7) ^ lrow) * 8);     // swizzled source col (elems)

  f32x4 acc[4][4];
#pragma unroll
  for (int i = 0; i < 4; i++)
#pragma unroll
    for (int j = 0; j < 4; j++) acc[i][j] = (f32x4){0.f, 0.f, 0.f, 0.f};

  for (int k0 = 0; k0 < HID; k0 += 64) {
#pragma unroll
    for (int it = 0; it < 4; it++) {
      const int r0 = (it * 4 + wave) * 8;
      gl2lds16(Ag + (size_t)(r0 + lrow) * HID + k0 + scol, &As[(it * 4 + wave) * 512]);
      gl2lds16(Bg + (size_t)(r0 + lrow) * HID + k0 + scol, &Bs[(it * 4 + wave) * 512]);
    }
    __syncthreads();
#pragma unroll
    for (int kk = 0; kk < 2; kk++) {
      const int pu = (((kk * 4 + hi) ^ (lo & 7)) * 8);
      s16x8 af[4], bf[4];
#pragma unroll
      for (int i = 0; i < 4; i++)
        af[i] = *(const s16x8*)(&As[(wr * 64 + i * 16 + lo) * 64 + pu]);
#pragma unroll
      for (int j = 0; j < 4; j++)
        bf[j] = *(const s16x8*)(&Bs[(wc * 64 + j * 16 + lo) * 64 + pu]);
#pragma unroll
      for (int i = 0; i < 4; i++)
#pragma unroll
        for (int j = 0; j < 4; j++)
          acc[i][j] = MFMA_BF16(af[i], bf[j], acc[i][j]);
    }
    __syncthreads();
  }

  if (z != 2) {
    ushort_t* out = (z == 0) ? Qp : Kp;
#pragma unroll
    for (int j = 0; j < 4; j++) {
      const int n = nb * 128 + wc * 64 + j * 16 + lo;
      const float bvn = bias[n];
      const int h = n >> 6, d = n & 63;
#pragma unroll
      for (int i = 0; i < 4; i++) {
        const int m0 = mb * 128 + wr * 64 + i * 16 + hi * 4;
#pragma unroll
        for (int r = 0; r < 4; r++) {
          const int m = m0 + r;
          const int b = m >> 11, s = m & 2047;
          float v = (acc[i][j][r] + bvn) * scale;
          __builtin_nontemporal_store(
              f2bf(v), out + (((size_t)(b * NHEAD + h) * SEQ) + s) * HEADD + d);
        }
      }
    }
  } else {
#pragma unroll
    for (int j = 0; j < 4; j++) {
      const int n = nb * 128 + wc * 64 + j * 16 + lo;
      const float bvn = bias[n];
      const int h = n >> 6, d = n & 63;
#pragma unroll
      for (int i = 0; i < 4; i++) {
        const int m0 = mb * 128 + wr * 64 + i * 16 + hi * 4;
        const int b = m0 >> 11, s0 = m0 & 2047;
        u16x4 pk = {f2bf(acc[i][j][0] + bvn), f2bf(acc[i][j][1] + bvn),
                    f2bf(acc[i][j][2] + bvn), f2bf(acc[i][j][3] + bvn)};
        __builtin_nontemporal_store(
            pk, (u16x4*)(Vp + ((size_t)(b * NHEAD + h) * HEADD + d) * SEQ + s0));
      }
    }
  }
}

// ---------------------------------------------------------------------------
// Fused attention. Sweep1 + finalize: EXACT R10 (verified best).
// Sweep2 NEW: identical 16x16 QK^T, but results are repacked through
// now-idle LDS ([32][65] f32 per wave, wave-private, no barriers) so each
// store instruction writes ONE ROW x 64 cols = 256B CONTIGUOUS (vs 4
// scattered 64B segments). mi crosses layouts via wave-private LDS.
// ---------------------------------------------------------------------------
__global__ __launch_bounds__(256, 2) void fused_attn_kernel(
    const ushort_t* __restrict__ Qp, const ushort_t* __restrict__ Kp,
    const ushort_t* __restrict__ Vtg, const u64* __restrict__ pm,
    float* __restrict__ attn, float* __restrict__ ctx) {
  extern __shared__ ushort_t smem[];
  ushort_t* Vt = smem;           // [64][136] linear+pad  = 8704 elems
  ushort_t* Ps = smem + 8704;    // [128][136] swizzled   = 17408 elems
  // sweep2 aliases (used only after sweep1's final barrier):
  float* stgf   = (float*)smem;            // 4 x [32][65] f32 = 33280 B
  float* mi_lds = stgf + 4 * 2080;         // 128 f32 (wave-private slices)

  const int tid  = threadIdx.x;
  const int lane = tid & 63, wave = tid >> 6;
  const int lo = lane & 15, hi = lane >> 4;

  const int f   = blockIdx.x;                 // 0..1023
  const int xcd = f & 7, i5 = f >> 3;         // i5: 0..127
  const int bh  = xcd * 8 + (i5 & 7);
  const int qb  = i5 >> 3;                    // 0..15
  const int b = bh >> 4, h = bh & 15;

  const ushort_t* Qg = Qp + ((size_t)bh * SEQ + qb * 128 + wave * 32) * HEADD;
  s16x8 aq[2][2];
#pragma unroll
  for (int i = 0; i < 2; i++)
#pragma unroll
    for (int kk = 0; kk < 2; kk++)
      aq[i][kk] = *(const s16x8*)(Qg + (size_t)(i * 16 + lo) * HEADD + kk * 32 + hi * 8);

  const ushort_t* Kg = Kp + (size_t)bh * SEQ * HEADD;          // [s][d]
  const ushort_t* Vg = Vtg + (size_t)bh * HEADD * SEQ;         // [d][s]
  const u64* pmb = pm + (size_t)b * SEQ * 32;
  const int q0 = qb * 128 + wave * 32;

  float lrun[2][4];
#pragma unroll
  for (int i = 0; i < 2; i++)
#pragma unroll
    for (int r = 0; r < 4; r++) lrun[i][r] = 0.f;
  f32x4 pacc[2][4];
#pragma unroll
  for (int i = 0; i < 2; i++)
#pragma unroll
    for (int jd = 0; jd < 4; jd++) pacc[i][jd] = (f32x4){0.f, 0.f, 0.f, 0.f};

  const int vr16 = tid >> 4;         // 0..15 (V d-row base)
  const int vc8  = (tid & 15) * 8;   // 0..120 (V s-col)

  // ================= sweep 1: l + PV (unnormalized) =================
  for (int kt = 0; kt < SEQ / 128; kt++) {
    u16x8 vreg[4];
#pragma unroll
    for (int it = 0; it < 4; it++)
      vreg[it] = *(const u16x8*)(Vg + (size_t)(it * 16 + vr16) * SEQ + kt * 128 + vc8);

    f32x4 sacc[2][8];
#pragma unroll
    for (int i = 0; i < 2; i++)
#pragma unroll
      for (int j = 0; j < 8; j++) sacc[i][j] = (f32x4){0.f, 0.f, 0.f, 0.f};
#pragma unroll
    for (int j = 0; j < 8; j++) {
      const ushort_t* kr = Kg + (size_t)(kt * 128 + j * 16 + lo) * HEADD + hi * 8;
      s16x8 b0 = *(const s16x8*)(kr);
      s16x8 b1 = *(const s16x8*)(kr + 32);
      sacc[0][j] = MFMA_BF16(aq[0][0], b0, sacc[0][j]);
      sacc[1][j] = MFMA_BF16(aq[1][0], b0, sacc[1][j]);
      sacc[0][j] = MFMA_BF16(aq[0][1], b1, sacc[0][j]);
      sacc[1][j] = MFMA_BF16(aq[1][1], b1, sacc[1][j]);
    }

#pragma unroll
    for (int it = 0; it < 4; it++)
      *(u16x8*)(&Vt[(it * 16 + vr16) * 136 + vc8]) = vreg[it];

#pragma unroll
    for (int i = 0; i < 2; i++)
#pragma unroll
      for (int r = 0; r < 4; r++) {
        const int q = q0 + i * 16 + hi * 4 + r;
        const u64* pw = pmb + (size_t)q * 32 + kt * 2;
        u64 s0 = pw[0] >> lo, s1 = pw[1] >> lo;
        const int prow = wave * 32 + i * 16 + hi * 4 + r;
        float tsum = 0.f;
#pragma unroll
        for (int j = 0; j < 8; j++) {
          unsigned bit = (unsigned)((j < 4 ? (s0 >> (j * 16)) : (s1 >> ((j - 4) * 16))) & 1ull);
          float s = bit ? sacc[i][j][r] : -1e30f;
          float ev = __builtin_amdgcn_exp2f(s);
          tsum += ev;
          Ps[ps_off(prow, j * 16 + lo)] = f2bf(ev);
        }
        lrun[i][r] += tsum;
      }
    __syncthreads();   // Ps + Vt visible

#pragma unroll
    for (int kkp = 0; kkp < 4; kkp++) {
      const int ko = kkp * 32 + hi * 8;
      s16x8 ap0 = *(const s16x8*)(&Ps[ps_off(wave * 32 + lo, ko)]);
      s16x8 ap1 = *(const s16x8*)(&Ps[ps_off(wave * 32 + 16 + lo, ko)]);
#pragma unroll
      for (int jd = 0; jd < 4; jd++) {
        s16x8 bv = *(const s16x8*)(&Vt[(jd * 16 + lo) * 136 + ko]);
        pacc[0][jd] = MFMA_BF16(ap0, bv, pacc[0][jd]);
        pacc[1][jd] = MFMA_BF16(ap1, bv, pacc[1][jd]);
      }
    }
    __syncthreads();   // Ps/Vt consumed; after final iter all waves are past
  }                    // LDS use -> safe to alias stgf/mi_lds (wave-private)

  // ---- finalize: l, ctx = pacc/l (nt), mi -> wave-private LDS ----
  float il[2][4];
#pragma unroll
  for (int i = 0; i < 2; i++)
#pragma unroll
    for (int r = 0; r < 4; r++) {
      float l = lrun[i][r];
#pragma unroll
      for (int off = 1; off < 16; off <<= 1) l += __shfl_xor(l, off);
      il[i][r] = 1.0f / l;
      if (lo == 0)
        mi_lds[wave * 32 + i * 16 + hi * 4 + r] = __builtin_amdgcn_logf(l);  // log2
    }
#pragma unroll
  for (int i = 0; i < 2; i++)
#pragma unroll
    for (int jd = 0; jd < 4; jd++)
#pragma unroll
      for (int r = 0; r < 4; r++) {
        const int q = q0 + i * 16 + hi * 4 + r;
        __builtin_nontemporal_store(
            pacc[i][jd][r] * il[i][r],
            ctx + ((size_t)b * SEQ + q) * HID + h * HEADD + jd * 16 + lo);
      }

  // ===== sweep 2: attn = exp2(s - mi), LDS-repacked 256B-contiguous stores ==
  float* stg = stgf + wave * 2080;   // [32][65] f32, wave-private
  for (int kt = 0; kt < SEQ / 128; kt++) {
    f32x4 sacc[2][8];
#pragma unroll
    for (int i = 0; i < 2; i++)
#pragma unroll
      for (int j = 0; j < 8; j++) sacc[i][j] = (f32x4){0.f, 0.f, 0.f, 0.f};
#pragma unroll
    for (int j = 0; j < 8; j++) {
      const ushort_t* kr = Kg + (size_t)(kt * 128 + j * 16 + lo) * HEADD + hi * 8;
      s16x8 b0 = *(const s16x8*)(kr);
      s16x8 b1 = *(const s16x8*)(kr + 32);
      sacc[0][j] = MFMA_BF16(aq[0][0], b0, sacc[0][j]);
      sacc[1][j] = MFMA_BF16(aq[1][0], b0, sacc[1][j]);
      sacc[0][j] = MFMA_BF16(aq[0][1], b1, sacc[0][j]);
      sacc[1][j] = MFMA_BF16(aq[1][1], b1, sacc[1][j]);
    }
#pragma unroll
    for (int hh = 0; hh < 2; hh++) {
      // Phase A: stage raw scores row-major [32][65] (wave-private; in-wave
      // DS ordering + compiler lgkmcnt handles RAW/WAR, no barrier needed)
#pragma unroll
      for (int i = 0; i < 2; i++)
#pragma unroll
        for (int j4 = 0; j4 < 4; j4++)
#pragma unroll
          for (int r = 0; r < 4; r++)
            stg[(i * 16 + hi * 4 + r) * 65 + j4 * 16 + lo] = sacc[i][hh * 4 + j4][r];
      // Phase B: one row per iteration; 64 lanes = 256B contiguous store
#pragma unroll
      for (int rl = 0; rl < 32; rl++) {
        const int q = q0 + rl;
        const float s = stg[rl * 65 + lane];
        const u64 w = pmb[(size_t)q * 32 + kt * 2 + hh];
        const float miv = mi_lds[wave * 32 + rl];
        const float e =
            ((w >> lane) & 1ull) ? __builtin_amdgcn_exp2f(s - miv) : 0.f;
        __builtin_nontemporal_store(
            e, attn + ((size_t)bh * SEQ + q) * SEQ + kt * 128 + hh * 64 + lane);
      }
    }
  }
}

// ---------------------------------------------------------------------------
extern "C" void kernel_launch(void* const* d_in, const int* in_sizes, int n_in,
                              void* d_out, int out_size, void* d_ws, size_t ws_size,
                              hipStream_t stream) {
  const float* query  = (const float*)d_in[0];
  const float* key_in = (const float*)d_in[1];
  const float* value  = (const float*)d_in[2];
  const int*   mask   = (const int*)d_in[3];
  const float* w_q = (const float*)d_in[4];
  const float* b_q = (const float*)d_in[5];
  const float* w_k = (const float*)d_in[6];
  const float* b_k = (const float*)d_in[7];
  const float* w_v = (const float*)d_in[8];
  const float* b_v = (const float*)d_in[9];

  char* ws = (char*)d_ws;
  const size_t proj_elems = (size_t)BATCH * NHEAD * SEQ * HEADD;  // 8388608
  ushort_t* Qp = (ushort_t*)ws;
  ushort_t* Kp = Qp + proj_elems;
  ushort_t* Vp = Kp + proj_elems;          // [B][H][D][S] transposed
  u64* pmask   = (u64*)(ws + 3 * proj_elems * sizeof(ushort_t));

  float* ctx  = (float*)d_out;                         // [B][S][HID]
  float* attn = ctx + (size_t)BATCH * SEQ * HID;       // [B][H][S][S]

  // bf16 prepack scratch lives in d_out's attn region (read by the GEMM,
  // overwritten afterwards by the attn kernel). Sequential + deterministic.
  ushort_t* Xb = (ushort_t*)attn;                         // 3 x 8.4M bf16
  ushort_t* Wb = Xb + (size_t)3 * MROWS * HID;            // 3 x 1M bf16

  prepack_kernel<<<dim3(512, 1, 4), dim3(256), 0, stream>>>(
      query, key_in, value, w_q, w_k, w_v, Xb, Wb, mask, pmask);

  proj_gemm_kernel<<<dim3(HID / 128, MROWS / 128, 3), dim3(256), 0, stream>>>(
      Xb, Wb, b_q, b_k, b_v, Qp, Kp, Vp);

  const size_t lds_attn = (8704 + 17408) * sizeof(ushort_t);  // 52224 B
  fused_attn_kernel<<<dim3(BH * (SEQ / 128)), dim3(256), lds_attn, stream>>>(
      Qp, Kp, Vp, pmask, attn, ctx);
}